// Round 4
// baseline (184.503 us; speedup 1.0000x reference)
//
#include <hip/hip_runtime.h>

// CIN fused 3-layer, bf16 MFMA (R10): R8 frame + ks-split waves + global xr.
// cur[sl,n] = sum_f x_f[sl] * S_f[sl,n],  S_f = sum_g h_g[sl] * W[f*64+g, n].
//
// R9 post-mortem: compiler dropped to 64 VGPR, re-read h-frags from LDS each
// iter (bank conflicts 105K->975K), 50 us. Reverted structure.
// R8 post-mortem: LDS-pipe bound (~900 cy/f/CU LDS vs 310 cy MFMA):
//   32 B-frag b128 (m-half waves read every frag TWICE) + 32 xr b128 + DMA.
//
// R10 (keeps R8's 256 blocks x 1024 thr, global_load_lds dbuf staging):
//  - ks-split: 16 waves = 8 n-tiles x 2 ks-halves; each wave all 4 m-tiles,
//    ONE un-chained MFMA per (mt,f) on its ks-half. B-frag reads 32->16/f/CU.
//    Partial cur summed once per layer via component-sliced rbuf (32 KB,
//    conflict-free b32: consecutive lanes -> consecutive dwords). Valid by
//    linearity: cur = sum_f x_f*(S0+S1) = sum_f x_f*S0 + sum_f x_f*S1.
//  - xr via GLOBAL dwordx4 (L1/L2-resident 10 KB x-slice), depth-2 register
//    rotation -> xr LDS reads 32->0/f/CU. LDS pipe ~900 -> ~320 cy/f.
//
// wt layout (prep output), tile tl = l*39+f (layer0 g zero-padded):
//   wt[tl*8192 + ((ks*4 + q)*128 + n)*8 + j] = bf16(W_l[f*64 + ks*32+q*8+j][n])

#define NF      39
#define LCH     128
#define NLAYER  3
#define NFT     (NLAYER * NF)    // 117 f-tiles
#define TILE_SH 8192             // shorts per B tile (16 KB)
#define PH_T    3                // tiles per phase
#define BUF_SH  (PH_T * TILE_SH) // 24576 shorts per buffer (48 KB)
#define SLN     64               // slices per block (4 batches x 16 d)
#define NPH     (NF / PH_T)      // 13 phases per layer

typedef __bf16        bf16x8 __attribute__((ext_vector_type(8)));
typedef unsigned int  uint4v __attribute__((ext_vector_type(4)));
typedef float         f32x4  __attribute__((ext_vector_type(4)));

__device__ __forceinline__ unsigned short f2bf_rne(float f) {
    unsigned u = __float_as_uint(f);
    u += 0x7fffu + ((u >> 16) & 1u);
    return (unsigned short)(u >> 16);
}

// ---------------- prep: W fp32 -> bf16 frag-ready tiles in ws ----------------
__global__ void cin_prep(const float* __restrict__ W0,
                         const float* __restrict__ W1,
                         const float* __restrict__ W2,
                         unsigned short* __restrict__ wt)
{
    const int t = blockIdx.x * blockDim.x + threadIdx.x; // ((tl*2+ks)*4+q)*128 + n
    if (t >= NFT * 1024) return;
    const int n  = t & 127;
    const int q  = (t >> 7) & 3;
    const int ks = (t >> 9) & 1;
    const int tl = t >> 10;
    const int l  = tl / NF;
    const int f  = tl - l * NF;
    const float* W = (l == 0) ? W0 : (l == 1) ? W1 : W2;

    unsigned short v[8];
    #pragma unroll
    for (int j = 0; j < 8; ++j) {
        const int g = ks * 32 + q * 8 + j;
        float w = 0.0f;
        if (l == 0) { if (g < NF) w = W[(f * NF + g) * LCH + n]; }
        else        { w = W[(f * 64 + g) * LCH + n]; }
        v[j] = f2bf_rne(w);
    }
    uint4v pv;
    #pragma unroll
    for (int i = 0; i < 4; ++i)
        pv[i] = (unsigned)v[2 * i] | ((unsigned)v[2 * i + 1] << 16);
    ((uint4v*)wt)[t] = pv;   // 16B coalesced
}

// ---------------- main ----------------
__global__ __launch_bounds__(1024, 4) void cin_mfma(
    const float* __restrict__ x,
    const unsigned short* __restrict__ wt,
    const float* __restrict__ b0p,
    const float* __restrict__ b1p,
    const float* __restrict__ b2p,
    float* __restrict__ out)
{
    __shared__ __align__(16) unsigned short Bbuf[2 * BUF_SH];   // 96 KB B dbuf
    __shared__ __align__(16) unsigned short hfrag[8 * SLN * 8]; // 8 KB
    __shared__ __align__(16) float rbuf[16 * 512];              // 32 KB ks exch

    const int tid  = threadIdx.x;
    const int lane = tid & 63;
    const int w    = tid >> 6;      // wave 0..15
    const int wn   = w & 7;         // n-tile
    const int ksh  = w >> 3;        // ks-half
    const int q    = lane >> 4;     // quad 0..3
    const int c    = lane & 15;
    const int nc   = wn * 16 + c;   // this lane's output channel
    const int bb   = blockIdx.x * 4;

    // zero hfrag (covers layer-0 padding g in [39,64)): 8 KB = 512 * 16B
    if (tid < 512) {
        f32x4 z4 = {0.f, 0.f, 0.f, 0.f};
        ((f32x4*)hfrag)[tid] = z4;
    }
    __syncthreads();

    // stage layer-0 h (bf16) from x (contiguous 4*39*16 = 2496 floats)
    for (int i = tid; i < 4 * NF * 16; i += 1024) {
        const float v = x[bb * (NF * 16) + i];
        const int lb = i / (NF * 16);
        const int r  = i - lb * (NF * 16);
        const int f  = r >> 4;
        const int d  = r & 15;
        const int sl = lb * 16 + d;
        hfrag[((f >> 3) * SLN + sl) * 8 + (f & 7)] = f2bf_rne(v);
    }

    // issue initial B staging: tiles 0..2 -> buf0 (16 waves x 1 KB per tile)
    {
        const unsigned short* src = wt + w * 512 + lane * 8;
        unsigned short* dst = Bbuf + w * 512;
        #pragma unroll
        for (int k = 0; k < PH_T; ++k)
            __builtin_amdgcn_global_load_lds((const void*)(src + k * TILE_SH),
                                             (void*)(dst + k * TILE_SH), 16, 0, 0);
    }

    // xr global base: x[(bb+mt)*624 + f*16 + q*4 .. +3], 16B aligned
    const float* xb = x + bb * (NF * 16) + q * 4;

    __syncthreads();   // hfrag + buf0 ready

    int cb = 0;
    #pragma unroll 1
    for (int l = 0; l < NLAYER; ++l) {
        // hoist A-frags for OWN ks-half only (4 frags = 16 VGPR)
        bf16x8 a[4];
        #pragma unroll
        for (int mt = 0; mt < 4; ++mt)
            a[mt] = *(const bf16x8*)&hfrag[((ksh * 4 + q) * SLN + mt * 16 + c) * 8];

        f32x4 cur[4];
        #pragma unroll
        for (int mt = 0; mt < 4; ++mt) cur[mt] = f32x4{0.f, 0.f, 0.f, 0.f};
        const f32x4 zz = {0.f, 0.f, 0.f, 0.f};

        // prime xr depth-2 rotation (x is layer-invariant)
        f32x4 xc[4], xn[4];
        #pragma unroll
        for (int mt = 0; mt < 4; ++mt) {
            xc[mt] = *(const f32x4*)(xb + mt * (NF * 16));
            xn[mt] = *(const f32x4*)(xb + mt * (NF * 16) + 16);
        }

        #pragma unroll 1
        for (int ph = 0; ph < NPH; ++ph) {
            const int tl = l * NF + ph * PH_T;

            // issue next phase's staging first (issue-early / drain-late)
            const int nb = tl + PH_T;
            if (nb < NFT) {
                const unsigned short* src = wt + (size_t)nb * TILE_SH + w * 512 + lane * 8;
                unsigned short* dst = &Bbuf[(cb ^ 1) * BUF_SH + w * 512];
                #pragma unroll
                for (int k = 0; k < PH_T; ++k)
                    __builtin_amdgcn_global_load_lds((const void*)(src + k * TILE_SH),
                                                     (void*)(dst + k * TILE_SH), 16, 0, 0);
            }

            // B-frags for this phase's 3 tiles, OWN ks-half only (from LDS)
            const unsigned short* rbq = Bbuf + cb * BUF_SH + ((ksh * 4 + q) * 128 + nc) * 8;
            const bf16x8 B0 = *(const bf16x8*)(rbq);
            const bf16x8 B1 = *(const bf16x8*)(rbq + TILE_SH);
            const bf16x8 B2 = *(const bf16x8*)(rbq + 2 * TILE_SH);

            #define F_ITER(BK, FI)                                                  \
            {                                                                       \
                _Pragma("unroll")                                                   \
                for (int mt = 0; mt < 4; ++mt) {                                    \
                    const f32x4 sv = __builtin_amdgcn_mfma_f32_16x16x32_bf16(       \
                        a[mt], BK, zz, 0, 0, 0);                                    \
                    _Pragma("unroll")                                               \
                    for (int r = 0; r < 4; ++r)                                     \
                        cur[mt][r] = fmaf(xc[mt][r], sv[r], cur[mt][r]);            \
                }                                                                   \
                int fn = (FI) + 2; if (fn > NF - 1) fn = NF - 1;                    \
                _Pragma("unroll")                                                   \
                for (int mt = 0; mt < 4; ++mt) {                                    \
                    xc[mt] = xn[mt];                                                \
                    xn[mt] = *(const f32x4*)(xb + mt * (NF * 16) + fn * 16);        \
                }                                                                   \
            }
            F_ITER(B0, ph * PH_T + 0)
            F_ITER(B1, ph * PH_T + 1)
            F_ITER(B2, ph * PH_T + 2)
            #undef F_ITER

            __syncthreads();   // drain staging + buffer handoff
            cb ^= 1;
        }

        // ---------------- layer end: ks-half reduce + epilogue ----------------
        if (ksh == 1) {
            // component-sliced: consecutive lanes -> consecutive dwords (no conflicts)
            #pragma unroll
            for (int mt = 0; mt < 4; ++mt)
                #pragma unroll
                for (int r = 0; r < 4; ++r)
                    rbuf[(mt * 4 + r) * 512 + wn * 64 + lane] = cur[mt][r];
        }
        __syncthreads();
        if (ksh == 0) {
            const float* bp = (l == 0) ? b0p : (l == 1) ? b1p : b2p;
            const float bias = bp[nc];
            float v[4][4];
            #pragma unroll
            for (int mt = 0; mt < 4; ++mt)
                #pragma unroll
                for (int r = 0; r < 4; ++r)
                    v[mt][r] = fmaxf(cur[mt][r] +
                                     rbuf[(mt * 4 + r) * 512 + wn * 64 + lane] +
                                     bias, 0.f);

            if (l < 2 && wn < 4) {
                // h channels (nc < 64): write next layer's h (C row = q*4+r)
                #pragma unroll
                for (int mt = 0; mt < 4; ++mt)
                    #pragma unroll
                    for (int r = 0; r < 4; ++r)
                        hfrag[((nc >> 3) * SLN + mt * 16 + q * 4 + r) * 8 + (nc & 7)] =
                            f2bf_rne(v[mt][r]);
            } else {
                // direct channels: reduce over d (= q*4+r) and store
                // l==0: nc 64..127 -> out 0..63 ; l==1: nc 64..127 -> out 64..127 ;
                // l==2: nc 0..127 -> out 128..255
                const int outcol = (l == 0) ? nc - 64 : (l == 1) ? nc : 128 + nc;
                #pragma unroll
                for (int mt = 0; mt < 4; ++mt) {
                    float sacc = v[mt][0] + v[mt][1] + v[mt][2] + v[mt][3];
                    sacc += __shfl_xor(sacc, 16, 64);
                    sacc += __shfl_xor(sacc, 32, 64);
                    if (lane < 16) out[(bb + mt) * 256 + outcol] = sacc;
                }
            }
        }
        if (l < 2) __syncthreads();   // h writes visible before next A-hoist
    }
}

extern "C" void kernel_launch(void* const* d_in, const int* in_sizes, int n_in,
                              void* d_out, int out_size, void* d_ws, size_t ws_size,
                              hipStream_t stream) {
    const float* x  = (const float*)d_in[0];
    const float* W0 = (const float*)d_in[1];
    const float* W1 = (const float*)d_in[2];
    const float* W2 = (const float*)d_in[3];
    const float* b0 = (const float*)d_in[4];
    const float* b1 = (const float*)d_in[5];
    const float* b2 = (const float*)d_in[6];
    float* out = (float*)d_out;
    unsigned short* wt = (unsigned short*)d_ws;  // 117*8192*2 B = 1.87 MB

    const int prep_threads = NFT * 1024;         // 119808
    cin_prep<<<(prep_threads + 255) / 256, 256, 0, stream>>>(W0, W1, W2, wt);
    cin_mfma<<<256, 1024, 0, stream>>>(x, wt, b0, b1, b2, out);
}